// Round 2
// baseline (12386.686 us; speedup 1.0000x reference)
//
#include <hip/hip_runtime.h>

#define Bv    64
#define Sv    200
#define DKv   32
#define NQ1v  4097
#define NWG   8      // workgroups per batch element
#define TPB   256    // threads per workgroup
#define ROWS  2      // rows per thread: 8*256*2 = 4096, +1 special
#define NSTEP 199

__device__ __forceinline__ float fsig(float x) {
  return __builtin_amdgcn_rcpf(1.0f + __builtin_amdgcn_exp2f(x * -1.4426950408889634f));
}
__device__ __forceinline__ float ftanh_(float x) {
  return fmaf(2.0f, fsig(2.0f * x), -1.0f);
}

__global__ void lpkt_init(unsigned int* cnt, float* out) {
  int i = threadIdx.x;
  if (i < Bv) { cnt[i * 16] = 0u; out[i * Sv] = 0.0f; }
}

__global__ __launch_bounds__(TPB, 2) void lpkt_main(
    const int* __restrict__ e_data, const int* __restrict__ at_data,
    const int* __restrict__ it_data, const float* __restrict__ a_data,
    const float* __restrict__ q_matrix,
    const float* __restrict__ E_e, const float* __restrict__ E_at, const float* __restrict__ E_it,
    const float* __restrict__ W1, const float* __restrict__ b1,
    const float* __restrict__ W2, const float* __restrict__ b2,
    const float* __restrict__ W3, const float* __restrict__ b3,
    const float* __restrict__ W4, const float* __restrict__ b4,
    const float* __restrict__ W5, const float* __restrict__ b5,
    const float* __restrict__ h0, float* __restrict__ out,
    float* __restrict__ partial, unsigned int* __restrict__ cnt)
{
  const int tid = threadIdx.x;
  const int wg  = blockIdx.x & (NWG - 1);
  const int b   = blockIdx.x / NWG;
  const int k   = tid & 31;
  const int p   = tid >> 5;          // 0..7
  const int nbase = wg * (TPB * ROWS);

  __shared__ __align__(16) float xw_lds[96];
  __shared__ __align__(16) float it_lds[DKv];
  __shared__ __align__(16) float lcA[DKv], lcB[DKv];
  __shared__ __align__(16) float ht_lds[DKv];
  __shared__ __align__(16) float LG_lds[DKv];
  __shared__ __align__(16) float c_lds[DKv];
  __shared__ __align__(16) float red[8][DKv];
  __shared__ __align__(16) float red2[8][DKv];
  __shared__ float ht_part[DKv];
  __shared__ __align__(16) float h49[DKv];
  __shared__ float W2T[128 * DKv];   // W2T[j][kk] = W2[kk][j], conflict-free reads
  __shared__ float W3T[128 * DKv];

  // ---- one-time: transpose W2/W3 into LDS; zero accumulators
  for (int idx = tid; idx < 128 * DKv; idx += TPB) {
    int kk = idx >> 7, j = idx & 127;
    W2T[j * DKv + kk] = W2[idx];
    W3T[j * DKv + kk] = W3[idx];
  }
  if (tid < DKv) { ht_part[tid] = 0.0f; lcB[tid] = 0.0f; }   // lcB = lp at t=0
  if (wg == 0 && tid < DKv) h49[tid] = h0[4096 * DKv + tid];

  // ---- persistent register state
  float h[ROWS][DKv];
#pragma unroll
  for (int r = 0; r < ROWS; r++) {
    const float4* hp = (const float4*)(h0 + (size_t)(nbase + r * TPB + tid) * DKv);
#pragma unroll
    for (int i = 0; i < 8; i++) {
      float4 v = hp[i];
      h[r][4*i] = v.x; h[r][4*i+1] = v.y; h[r][4*i+2] = v.z; h[r][4*i+3] = v.w;
    }
  }
  const int e0 = e_data[b * Sv];
  const float* q0 = q_matrix + (size_t)e0 * NQ1v;
  float qc[ROWS];
#pragma unroll
  for (int r = 0; r < ROWS; r++) qc[r] = q0[nbase + r * TPB + tid];
  float qc49 = (wg == 0 && tid < DKv) ? q0[4096] : 0.0f;
  __syncthreads();

  // ---- phase 0: h_tilde0 via sparse LDS atomics
#pragma unroll
  for (int r = 0; r < ROWS; r++) {
    if (qc[r] != 0.0f) {
#pragma unroll
      for (int kk = 0; kk < DKv; kk++) atomicAdd(&ht_part[kk], h[r][kk]);
    }
  }
  if (wg == 0 && tid < DKv && qc49 != 0.0f) atomicAdd(&ht_part[tid], h49[tid]);
  __syncthreads();
  if (tid < DKv)
    __hip_atomic_store(&partial[(((size_t)b * 2 + 0) * NWG + wg) * DKv + tid], ht_part[tid],
                       __ATOMIC_RELAXED, __HIP_MEMORY_SCOPE_AGENT);
  __threadfence();
  if (tid == 0)
    __hip_atomic_fetch_add(&cnt[b * 16], 1u, __ATOMIC_RELEASE, __HIP_MEMORY_SCOPE_AGENT);

  // =================== time loop ===================
  for (int t = 0; t < NSTEP; t++) {
    const int pbuf = t & 1;
    float* lc_cur  = (t & 1) ? lcB : lcA;
    float* lc_prev = (t & 1) ? lcA : lcB;

    // ---- A: prefetch q_next + stage embeddings (latency hidden under bulk)
    const int ecur  = e_data[b * Sv + t];
    const int enext = e_data[b * Sv + t + 1];
    const int atc   = at_data[b * Sv + t];
    const int itc   = it_data[b * Sv + t];
    const float av  = a_data[b * Sv + t];
    const float* qnr = q_matrix + (size_t)enext * NQ1v;
    float qn[ROWS];
#pragma unroll
    for (int r = 0; r < ROWS; r++) qn[r] = qnr[nbase + r * TPB + tid];
    float qn49 = (wg == 0 && tid < DKv) ? qnr[4096] : 0.0f;

    if (tid < 96)
      xw_lds[tid] = (tid < 32) ? E_e[(size_t)ecur * DKv + tid]
                  : (tid < 64) ? E_at[(size_t)atc * DKv + (tid - 32)] : av;
    else if (tid < 128)
      it_lds[tid - 96] = E_it[(size_t)itc * DKv + (tid - 96)];

    // ---- B: bulk matvec (no dependence on this step's sync)
    float acc[ROWS][DKv];
#pragma unroll
    for (int kk = 0; kk < DKv; kk++) {
      float a0 = 0.0f, a1 = 0.0f;
#pragma unroll
      for (int d = 0; d < DKv; d += 4) {
        float4 w = *(const float4*)&W4[kk * 96 + d];   // uniform -> s_load
        a0 = fmaf(w.x, h[0][d+0], a0); a1 = fmaf(w.x, h[1][d+0], a1);
        a0 = fmaf(w.y, h[0][d+1], a0); a1 = fmaf(w.y, h[1][d+1], a1);
        a0 = fmaf(w.z, h[0][d+2], a0); a1 = fmaf(w.z, h[1][d+2], a1);
        a0 = fmaf(w.w, h[0][d+3], a0); a1 = fmaf(w.w, h[1][d+3], a1);
      }
      acc[0][kk] = a0; acc[1][kk] = a1;
    }
    __syncthreads();   // B1: staging visible

    // ---- C: sync wait (should be near-instant: RTT overlapped by bulk)
    if (tid == 0) {
      unsigned target = (unsigned)NWG * (t + 1);
      while (__hip_atomic_load(&cnt[b * 16], __ATOMIC_ACQUIRE, __HIP_MEMORY_SCOPE_AGENT) < target)
        __builtin_amdgcn_s_sleep(1);
    }
    __syncthreads();   // B2

    // ---- S1: ht gather (lanes 0-31) | lc matvec (lanes 32-63)
    if (tid < DKv) {
      float s = 0.0f;
#pragma unroll
      for (int w2 = 0; w2 < NWG; w2++)
        s += __hip_atomic_load(&partial[(((size_t)b * 2 + pbuf) * NWG + w2) * DKv + tid],
                               __ATOMIC_RELAXED, __HIP_MEMORY_SCOPE_AGENT);
      ht_lds[tid] = s;
    } else if (tid < 64) {
      const int kx = tid - 32;
      float s = b1[kx];
      const float4* wp = (const float4*)&W1[kx * 96];
      const float4* xp = (const float4*)xw_lds;
#pragma unroll
      for (int i = 0; i < 24; i++) {
        float4 w = wp[i]; float4 x = xp[i];
        s = fmaf(x.x, w.x, s); s = fmaf(x.y, w.y, s);
        s = fmaf(x.z, w.z, s); s = fmaf(x.w, w.w, s);
      }
      lc_cur[kx] = s;
    }
    __syncthreads();   // B3

    // ---- D: lg/gl split-8 (16 inputs per part, conflict-free W2T/W3T reads)
    {
      const int seg = p >> 1;                     // 0:lp 1:it 2:lc 3:ht
      const float* sp = (seg == 0) ? lc_prev : (seg == 1) ? it_lds
                      : (seg == 2) ? lc_cur  : ht_lds;
      const int off = (p & 1) * 16;
      float xv[16];
#pragma unroll
      for (int i = 0; i < 4; i++) {
        float4 v = ((const float4*)(sp + off))[i];
        xv[4*i] = v.x; xv[4*i+1] = v.y; xv[4*i+2] = v.z; xv[4*i+3] = v.w;
      }
      float s2 = 0.0f, s3 = 0.0f;
      const int jb = 16 * p;
#pragma unroll
      for (int i = 0; i < 16; i++) {
        s2 = fmaf(xv[i], W2T[(jb + i) * DKv + k], s2);
        s3 = fmaf(xv[i], W3T[(jb + i) * DKv + k], s3);
      }
      red[p][k] = s2; red2[p][k] = s3;
    }
    __syncthreads();   // B4

    // ---- E: LG (lanes 0-31) | zero ht_part (lanes 32-63)
    if (tid < DKv) {
      float s2 = b2[tid], s3 = b3[tid];
#pragma unroll
      for (int pp = 0; pp < 8; pp++) { s2 += red[pp][tid]; s3 += red2[pp][tid]; }
      LG_lds[tid] = fsig(s3) * (ftanh_(s2) + 1.0f) * 0.5f;
    } else if (tid < 64) ht_part[tid - 32] = 0.0f;
    __syncthreads();   // B5

    // ---- F: c split-8 (64 inputs) | y partials (wg0, t>=1)
    {
      const float* up = (p < 4) ? (LG_lds + 8 * p) : (it_lds + 8 * (p - 4));
      const float4* wp = (const float4*)&W4[k * 96 + 32 + 8 * p];
      float4 w0 = wp[0], w1 = wp[1];
      float pc = 0.0f;
      pc = fmaf(up[0], w0.x, pc); pc = fmaf(up[1], w0.y, pc);
      pc = fmaf(up[2], w0.z, pc); pc = fmaf(up[3], w0.w, pc);
      pc = fmaf(up[4], w1.x, pc); pc = fmaf(up[5], w1.y, pc);
      pc = fmaf(up[6], w1.z, pc); pc = fmaf(up[7], w1.w, pc);
      red[p][k] = pc;
    }
    if (wg == 0 && t >= 1 && tid >= 64 && tid < 128) {
      const int p2 = p - 2;
      const float* zs = (p2 == 0) ? xw_lds : ht_lds;   // xw[0:32] = E_e[e_data[t]]
      const float4* wp = (const float4*)&W5[k * 64 + 32 * p2];
      float acc5 = 0.0f;
#pragma unroll
      for (int i = 0; i < 8; i++) {
        float4 w = wp[i]; float4 z = ((const float4*)zs)[i];
        acc5 = fmaf(z.x, w.x, acc5); acc5 = fmaf(z.y, w.y, acc5);
        acc5 = fmaf(z.z, w.z, acc5); acc5 = fmaf(z.w, w.w, acc5);
      }
      red2[p2][k] = acc5;
    }
    __syncthreads();   // B6

    // ---- G: c sum (lanes 0-31) | y finish (wg0, lanes 32-63)
    if (tid < DKv) {
      float s = b4[tid];
#pragma unroll
      for (int pp = 0; pp < 8; pp++) s += red[pp][tid];
      c_lds[tid] = s;
    } else if (wg == 0 && t >= 1 && tid < 64) {
      const int kx = tid - 32;
      float s = fsig(b5[kx] + red2[0][kx] + red2[1][kx]);
#pragma unroll
      for (int m = 1; m < 32; m <<= 1) s += __shfl_xor(s, m);
      if (tid == 32) out[b * Sv + t] = s * (1.0f / DKv);
    }
    __syncthreads();   // B7

    // ---- H: update h in place; sparse-atomic h_tilde contributions
    {
      float c_r[DKv], lg_r[DKv];
#pragma unroll
      for (int i = 0; i < 8; i++) {
        float4 cv = ((const float4*)c_lds)[i];
        float4 gv = ((const float4*)LG_lds)[i];
        c_r[4*i] = cv.x; c_r[4*i+1] = cv.y; c_r[4*i+2] = cv.z; c_r[4*i+3] = cv.w;
        lg_r[4*i] = gv.x; lg_r[4*i+1] = gv.y; lg_r[4*i+2] = gv.z; lg_r[4*i+3] = gv.w;
      }
#pragma unroll
      for (int r = 0; r < ROWS; r++) {
        const float qcr = qc[r];
#pragma unroll
        for (int kk = 0; kk < DKv; kk++) {
          float g = fsig(acc[r][kk] + c_r[kk]);
          h[r][kk] = fmaf(g, h[r][kk], qcr * lg_r[kk]);
        }
        if (qn[r] != 0.0f) {
#pragma unroll
          for (int kk = 0; kk < DKv; kk++) atomicAdd(&ht_part[kk], h[r][kk]);
        }
        qc[r] = qn[r];
      }
    }
    if (wg == 0 && tid < DKv) {      // special row 4096 (LDS-resident, wave0)
      float hh[DKv];
#pragma unroll
      for (int i = 0; i < 8; i++) {
        float4 v = ((const float4*)h49)[i];
        hh[4*i] = v.x; hh[4*i+1] = v.y; hh[4*i+2] = v.z; hh[4*i+3] = v.w;
      }
      float a = c_lds[tid];
#pragma unroll
      for (int d = 0; d < DKv; d += 4) {
        float4 w = *(const float4*)&W4[tid * 96 + d];
        a = fmaf(w.x, hh[d+0], a); a = fmaf(w.y, hh[d+1], a);
        a = fmaf(w.z, hh[d+2], a); a = fmaf(w.w, hh[d+3], a);
      }
      float hn = fmaf(fsig(a), h49[tid], qc49 * LG_lds[tid]);
      h49[tid] = hn;
      if (qn49 != 0.0f) atomicAdd(&ht_part[tid], hn);
      qc49 = qn49;
    }
    __syncthreads();   // B8

    // ---- I: post partial + counter (wait happens next step, after bulk)
    if (tid < DKv)
      __hip_atomic_store(&partial[(((size_t)b * 2 + (1 - pbuf)) * NWG + wg) * DKv + tid],
                         ht_part[tid], __ATOMIC_RELAXED, __HIP_MEMORY_SCOPE_AGENT);
    __threadfence();
    if (tid == 0)
      __hip_atomic_fetch_add(&cnt[b * 16], 1u, __ATOMIC_RELEASE, __HIP_MEMORY_SCOPE_AGENT);
  }

  // =================== epilogue: y for pred index 199 ===================
  if (tid == 0) {
    unsigned target = (unsigned)NWG * (NSTEP + 1);
    while (__hip_atomic_load(&cnt[b * 16], __ATOMIC_ACQUIRE, __HIP_MEMORY_SCOPE_AGENT) < target)
      __builtin_amdgcn_s_sleep(1);
  }
  __syncthreads();
  if (tid < DKv) {
    float s = 0.0f;
#pragma unroll
    for (int w2 = 0; w2 < NWG; w2++)
      s += __hip_atomic_load(&partial[(((size_t)b * 2 + 1) * NWG + w2) * DKv + tid],
                             __ATOMIC_RELAXED, __HIP_MEMORY_SCOPE_AGENT);
    ht_lds[tid] = s;
    xw_lds[tid] = E_e[(size_t)e_data[b * Sv + 199] * DKv + tid];
  }
  __syncthreads();
  if (wg == 0 && tid >= 64 && tid < 128) {
    const int p2 = p - 2;
    const float* zs = (p2 == 0) ? xw_lds : ht_lds;
    const float4* wp = (const float4*)&W5[k * 64 + 32 * p2];
    float acc5 = 0.0f;
#pragma unroll
    for (int i = 0; i < 8; i++) {
      float4 w = wp[i]; float4 z = ((const float4*)zs)[i];
      acc5 = fmaf(z.x, w.x, acc5); acc5 = fmaf(z.y, w.y, acc5);
      acc5 = fmaf(z.z, w.z, acc5); acc5 = fmaf(z.w, w.w, acc5);
    }
    red2[p2][k] = acc5;
  }
  __syncthreads();
  if (wg == 0 && tid >= 32 && tid < 64) {
    const int kx = tid - 32;
    float s = fsig(b5[kx] + red2[0][kx] + red2[1][kx]);
#pragma unroll
    for (int m = 1; m < 32; m <<= 1) s += __shfl_xor(s, m);
    if (tid == 32) out[b * Sv + 199] = s * (1.0f / DKv);
  }
}

extern "C" void kernel_launch(void* const* d_in, const int* in_sizes, int n_in,
                              void* d_out, int out_size, void* d_ws, size_t ws_size,
                              hipStream_t stream) {
  const int*   e_data   = (const int*)d_in[0];
  const int*   at_data  = (const int*)d_in[1];
  const int*   it_data  = (const int*)d_in[2];
  const float* a_data   = (const float*)d_in[3];
  const float* q_matrix = (const float*)d_in[4];
  const float* E_e      = (const float*)d_in[5];
  const float* E_at     = (const float*)d_in[6];
  const float* E_it     = (const float*)d_in[7];
  const float* W1 = (const float*)d_in[8];
  const float* b1 = (const float*)d_in[9];
  const float* W2 = (const float*)d_in[10];
  const float* b2 = (const float*)d_in[11];
  const float* W3 = (const float*)d_in[12];
  const float* b3 = (const float*)d_in[13];
  const float* W4 = (const float*)d_in[14];
  const float* b4 = (const float*)d_in[15];
  const float* W5 = (const float*)d_in[16];
  const float* b5 = (const float*)d_in[17];
  const float* h0 = (const float*)d_in[18];
  float* out = (float*)d_out;

  float* partial = (float*)d_ws;
  unsigned int* cnt = (unsigned int*)((char*)d_ws + (size_t)Bv * 2 * NWG * DKv * sizeof(float));

  lpkt_init<<<1, 64, 0, stream>>>(cnt, out);
  lpkt_main<<<dim3(Bv * NWG), dim3(TPB), 0, stream>>>(
      e_data, at_data, it_data, a_data, q_matrix, E_e, E_at, E_it,
      W1, b1, W2, b2, W3, b3, W4, b4, W5, b5, h0, out, partial, cnt);
}

// Round 3
// 5189.552 us; speedup vs baseline: 2.3869x; 2.3869x over previous
//
#include <hip/hip_runtime.h>

#define Bv    64
#define Sv    200
#define DKv   32
#define NQ1v  4097
#define NWG   8      // workgroups per batch element
#define TPB   256    // threads per workgroup
#define ROWS  2      // rows per thread: 8*256*2 = 4096, +1 special
#define NSTEP 199

typedef unsigned long long u64;

__device__ __forceinline__ float fsig(float x) {
  return __builtin_amdgcn_rcpf(1.0f + __builtin_amdgcn_exp2f(x * -1.4426950408889634f));
}
__device__ __forceinline__ float ftanh_(float x) {
  return fmaf(2.0f, fsig(2.0f * x), -1.0f);
}
__device__ __forceinline__ u64 packvt(float v, unsigned tag) {
  return ((u64)tag << 32) | (u64)__float_as_uint(v);
}

__global__ void lpkt_init(float* out) {
  int i = threadIdx.x;
  if (i < Bv) out[i * Sv] = 0.0f;
}

__global__ __launch_bounds__(TPB, 2) void lpkt_main(
    const int* __restrict__ e_data, const int* __restrict__ at_data,
    const int* __restrict__ it_data, const float* __restrict__ a_data,
    const float* __restrict__ q_matrix,
    const float* __restrict__ E_e, const float* __restrict__ E_at, const float* __restrict__ E_it,
    const float* __restrict__ W1, const float* __restrict__ b1,
    const float* __restrict__ W2, const float* __restrict__ b2,
    const float* __restrict__ W3, const float* __restrict__ b3,
    const float* __restrict__ W4, const float* __restrict__ b4,
    const float* __restrict__ W5, const float* __restrict__ b5,
    const float* __restrict__ h0, float* __restrict__ out,
    u64* __restrict__ partial)
{
  const int tid = threadIdx.x;
  const int wg  = blockIdx.x & (NWG - 1);
  const int b   = blockIdx.x / NWG;
  const int k   = tid & 31;
  const int p   = tid >> 5;          // 0..7
  const int nbase = wg * (TPB * ROWS);

  __shared__ __align__(16) float xw_lds[96];
  __shared__ __align__(16) float it_lds[DKv];
  __shared__ __align__(16) float lcA[DKv], lcB[DKv];
  __shared__ __align__(16) float ht_lds[DKv];
  __shared__ __align__(16) float LG_lds[DKv];
  __shared__ __align__(16) float c_lds[DKv];
  __shared__ __align__(16) float red[8][DKv];
  __shared__ __align__(16) float red2[8][DKv];
  __shared__ float ht_part[DKv];
  __shared__ __align__(16) float h49[DKv];
  __shared__ float W2T[128 * DKv];   // W2T[j][kk] = W2[kk][j], conflict-free reads
  __shared__ float W3T[128 * DKv];

  // ---- one-time: transpose W2/W3 into LDS; zero accumulators
  for (int idx = tid; idx < 128 * DKv; idx += TPB) {
    int kk = idx >> 7, j = idx & 127;
    W2T[j * DKv + kk] = W2[idx];
    W3T[j * DKv + kk] = W3[idx];
  }
  if (tid < DKv) { ht_part[tid] = 0.0f; lcB[tid] = 0.0f; }   // lcB = lp at t=0
  if (wg == 0 && tid < DKv) h49[tid] = h0[4096 * DKv + tid];

  // ---- persistent register state
  float h[ROWS][DKv];
#pragma unroll
  for (int r = 0; r < ROWS; r++) {
    const float4* hp = (const float4*)(h0 + (size_t)(nbase + r * TPB + tid) * DKv);
#pragma unroll
    for (int i = 0; i < 8; i++) {
      float4 v = hp[i];
      h[r][4*i] = v.x; h[r][4*i+1] = v.y; h[r][4*i+2] = v.z; h[r][4*i+3] = v.w;
    }
  }
  const int e0 = e_data[b * Sv];
  const float* q0 = q_matrix + (size_t)e0 * NQ1v;
  float qc[ROWS];
#pragma unroll
  for (int r = 0; r < ROWS; r++) qc[r] = q0[nbase + r * TPB + tid];
  float qc49 = (wg == 0 && tid < DKv) ? q0[4096] : 0.0f;
  __syncthreads();

  // ---- phase 0: h_tilde0 via sparse LDS atomics; post tag=1
#pragma unroll
  for (int r = 0; r < ROWS; r++) {
    if (qc[r] != 0.0f) {
#pragma unroll
      for (int kk = 0; kk < DKv; kk++) atomicAdd(&ht_part[kk], h[r][kk]);
    }
  }
  if (wg == 0 && tid < DKv && qc49 != 0.0f) atomicAdd(&ht_part[tid], h49[tid]);
  __syncthreads();
  if (tid < DKv)
    __hip_atomic_store(&partial[((size_t)(1 % 3) * Bv + b) * (NWG * DKv) + wg * DKv + tid],
                       packvt(ht_part[tid], 1u), __ATOMIC_RELAXED, __HIP_MEMORY_SCOPE_AGENT);

  // =================== time loop ===================
  for (int t = 0; t < NSTEP; t++) {
    float* lc_cur  = (t & 1) ? lcB : lcA;
    float* lc_prev = (t & 1) ? lcA : lcB;
    const unsigned tau_g = (unsigned)(t + 1);
    const unsigned tau_p = (unsigned)(t + 2);

    // ---- A: prefetch q_next + stage embeddings (latency hidden under bulk)
    const int ecur  = e_data[b * Sv + t];
    const int enext = e_data[b * Sv + t + 1];
    const int atc   = at_data[b * Sv + t];
    const int itc   = it_data[b * Sv + t];
    const float av  = a_data[b * Sv + t];
    const float* qnr = q_matrix + (size_t)enext * NQ1v;
    float qn[ROWS];
#pragma unroll
    for (int r = 0; r < ROWS; r++) qn[r] = qnr[nbase + r * TPB + tid];
    float qn49 = (wg == 0 && tid < DKv) ? qnr[4096] : 0.0f;

    if (tid < 96)
      xw_lds[tid] = (tid < 32) ? E_e[(size_t)ecur * DKv + tid]
                  : (tid < 64) ? E_at[(size_t)atc * DKv + (tid - 32)] : av;
    else if (tid < 128)
      it_lds[tid - 96] = E_it[(size_t)itc * DKv + (tid - 96)];

    // ---- B: bulk matvec (no dependence on this step's sync)
    float acc[ROWS][DKv];
#pragma unroll
    for (int kk = 0; kk < DKv; kk++) {
      float a0 = 0.0f, a1 = 0.0f;
#pragma unroll
      for (int d = 0; d < DKv; d += 4) {
        float4 w = *(const float4*)&W4[kk * 96 + d];   // uniform -> s_load
        a0 = fmaf(w.x, h[0][d+0], a0); a1 = fmaf(w.x, h[1][d+0], a1);
        a0 = fmaf(w.y, h[0][d+1], a0); a1 = fmaf(w.y, h[1][d+1], a1);
        a0 = fmaf(w.z, h[0][d+2], a0); a1 = fmaf(w.z, h[1][d+2], a1);
        a0 = fmaf(w.w, h[0][d+3], a0); a1 = fmaf(w.w, h[1][d+3], a1);
      }
      acc[0][kk] = a0; acc[1][kk] = a1;
    }
    __syncthreads();   // B1: staging visible

    // ---- S1: lc matvec (lanes 32-63) | poll+gather ht (lanes 0-31, fence-free)
    if (tid >= 32 && tid < 64) {
      const int kx = tid - 32;
      float s = b1[kx];
      const float4* wp = (const float4*)&W1[kx * 96];
      const float4* xp = (const float4*)xw_lds;
#pragma unroll
      for (int i = 0; i < 24; i++) {
        float4 w = wp[i]; float4 x = xp[i];
        s = fmaf(x.x, w.x, s); s = fmaf(x.y, w.y, s);
        s = fmaf(x.z, w.z, s); s = fmaf(x.w, w.w, s);
      }
      lc_cur[kx] = s;
    }
    if (tid < DKv) {
      const u64* pb = partial + ((size_t)(tau_g % 3) * Bv + b) * (NWG * DKv) + tid;
      u64 v[NWG];
      for (;;) {
        bool ok = true;
#pragma unroll
        for (int w2 = 0; w2 < NWG; w2++) {
          v[w2] = __hip_atomic_load(&pb[w2 * DKv], __ATOMIC_RELAXED, __HIP_MEMORY_SCOPE_AGENT);
          ok = ok && ((unsigned)(v[w2] >> 32) == tau_g);
        }
        if (ok) break;
        __builtin_amdgcn_s_sleep(2);
      }
      float s = 0.0f;
#pragma unroll
      for (int w2 = 0; w2 < NWG; w2++) s += __uint_as_float((unsigned)v[w2]);
      ht_lds[tid] = s;
    }
    __syncthreads();   // B3

    // ---- D: lg/gl split-8 (conflict-free W2T/W3T reads)
    {
      const int seg = p >> 1;                     // 0:lp 1:it 2:lc 3:ht
      const float* sp = (seg == 0) ? lc_prev : (seg == 1) ? it_lds
                      : (seg == 2) ? lc_cur  : ht_lds;
      const int off = (p & 1) * 16;
      float xv[16];
#pragma unroll
      for (int i = 0; i < 4; i++) {
        float4 v = ((const float4*)(sp + off))[i];
        xv[4*i] = v.x; xv[4*i+1] = v.y; xv[4*i+2] = v.z; xv[4*i+3] = v.w;
      }
      float s2 = 0.0f, s3 = 0.0f;
      const int jb = 16 * p;
#pragma unroll
      for (int i = 0; i < 16; i++) {
        s2 = fmaf(xv[i], W2T[(jb + i) * DKv + k], s2);
        s3 = fmaf(xv[i], W3T[(jb + i) * DKv + k], s3);
      }
      red[p][k] = s2; red2[p][k] = s3;
    }
    __syncthreads();   // B4

    // ---- E: LG (lanes 0-31) | zero ht_part (lanes 32-63)
    if (tid < DKv) {
      float s2 = b2[tid], s3 = b3[tid];
#pragma unroll
      for (int pp = 0; pp < 8; pp++) { s2 += red[pp][tid]; s3 += red2[pp][tid]; }
      LG_lds[tid] = fsig(s3) * (ftanh_(s2) + 1.0f) * 0.5f;
    } else if (tid < 64) ht_part[tid - 32] = 0.0f;
    __syncthreads();   // B5

    // ---- F: c split-8 (64 inputs) | y partials (wg0, t>=1)
    {
      const float* up = (p < 4) ? (LG_lds + 8 * p) : (it_lds + 8 * (p - 4));
      const float4* wp = (const float4*)&W4[k * 96 + 32 + 8 * p];
      float4 w0 = wp[0], w1 = wp[1];
      float pc = 0.0f;
      pc = fmaf(up[0], w0.x, pc); pc = fmaf(up[1], w0.y, pc);
      pc = fmaf(up[2], w0.z, pc); pc = fmaf(up[3], w0.w, pc);
      pc = fmaf(up[4], w1.x, pc); pc = fmaf(up[5], w1.y, pc);
      pc = fmaf(up[6], w1.z, pc); pc = fmaf(up[7], w1.w, pc);
      red[p][k] = pc;
    }
    if (wg == 0 && t >= 1 && tid >= 64 && tid < 128) {
      const int p2 = p - 2;
      const float* zs = (p2 == 0) ? xw_lds : ht_lds;   // xw[0:32] = E_e[e_data[t]]
      const float4* wp = (const float4*)&W5[k * 64 + 32 * p2];
      float acc5 = 0.0f;
#pragma unroll
      for (int i = 0; i < 8; i++) {
        float4 w = wp[i]; float4 z = ((const float4*)zs)[i];
        acc5 = fmaf(z.x, w.x, acc5); acc5 = fmaf(z.y, w.y, acc5);
        acc5 = fmaf(z.z, w.z, acc5); acc5 = fmaf(z.w, w.w, acc5);
      }
      red2[p2][k] = acc5;
    }
    __syncthreads();   // B6

    // ---- G: c sum (lanes 0-31) | y finish (wg0, lanes 32-63)
    if (tid < DKv) {
      float s = b4[tid];
#pragma unroll
      for (int pp = 0; pp < 8; pp++) s += red[pp][tid];
      c_lds[tid] = s;
    } else if (wg == 0 && t >= 1 && tid < 64) {
      const int kx = tid - 32;
      float s = fsig(b5[kx] + red2[0][kx] + red2[1][kx]);
#pragma unroll
      for (int m = 1; m < 32; m <<= 1) s += __shfl_xor(s, m);
      if (tid == 32) out[b * Sv + t] = s * (1.0f / DKv);
    }
    __syncthreads();   // B7

    // ---- H: update h in place; sparse-atomic h_tilde contributions
    {
      float c_r[DKv], lg_r[DKv];
#pragma unroll
      for (int i = 0; i < 8; i++) {
        float4 cv = ((const float4*)c_lds)[i];
        float4 gv = ((const float4*)LG_lds)[i];
        c_r[4*i] = cv.x; c_r[4*i+1] = cv.y; c_r[4*i+2] = cv.z; c_r[4*i+3] = cv.w;
        lg_r[4*i] = gv.x; lg_r[4*i+1] = gv.y; lg_r[4*i+2] = gv.z; lg_r[4*i+3] = gv.w;
      }
#pragma unroll
      for (int r = 0; r < ROWS; r++) {
        const float qcr = qc[r];
#pragma unroll
        for (int kk = 0; kk < DKv; kk++) {
          float g = fsig(acc[r][kk] + c_r[kk]);
          h[r][kk] = fmaf(g, h[r][kk], qcr * lg_r[kk]);
        }
        if (qn[r] != 0.0f) {
#pragma unroll
          for (int kk = 0; kk < DKv; kk++) atomicAdd(&ht_part[kk], h[r][kk]);
        }
        qc[r] = qn[r];
      }
    }
    if (wg == 0 && tid < DKv) {      // special row 4096 (LDS-resident, wave0)
      float hh[DKv];
#pragma unroll
      for (int i = 0; i < 8; i++) {
        float4 v = ((const float4*)h49)[i];
        hh[4*i] = v.x; hh[4*i+1] = v.y; hh[4*i+2] = v.z; hh[4*i+3] = v.w;
      }
      float a = c_lds[tid];
#pragma unroll
      for (int d = 0; d < DKv; d += 4) {
        float4 w = *(const float4*)&W4[tid * 96 + d];
        a = fmaf(w.x, hh[d+0], a); a = fmaf(w.y, hh[d+1], a);
        a = fmaf(w.z, hh[d+2], a); a = fmaf(w.w, hh[d+3], a);
      }
      float hn = fmaf(fsig(a), h49[tid], qc49 * LG_lds[tid]);
      h49[tid] = hn;
      if (qn49 != 0.0f) atomicAdd(&ht_part[tid], hn);
      qc49 = qn49;
    }
    __syncthreads();   // B8

    // ---- I: post tagged partial (relaxed 64-bit atomic, NO fence)
    if (tid < DKv)
      __hip_atomic_store(&partial[((size_t)(tau_p % 3) * Bv + b) * (NWG * DKv) + wg * DKv + tid],
                         packvt(ht_part[tid], tau_p), __ATOMIC_RELAXED, __HIP_MEMORY_SCOPE_AGENT);
  }

  // =================== epilogue: y for pred index 199 (wg0 only) ===================
  if (wg == 0) {
    const unsigned tau_f = (unsigned)(NSTEP + 1);   // 200
    if (tid < DKv) {
      const u64* pb = partial + ((size_t)(tau_f % 3) * Bv + b) * (NWG * DKv) + tid;
      u64 v[NWG];
      for (;;) {
        bool ok = true;
#pragma unroll
        for (int w2 = 0; w2 < NWG; w2++) {
          v[w2] = __hip_atomic_load(&pb[w2 * DKv], __ATOMIC_RELAXED, __HIP_MEMORY_SCOPE_AGENT);
          ok = ok && ((unsigned)(v[w2] >> 32) == tau_f);
        }
        if (ok) break;
        __builtin_amdgcn_s_sleep(2);
      }
      float s = 0.0f;
#pragma unroll
      for (int w2 = 0; w2 < NWG; w2++) s += __uint_as_float((unsigned)v[w2]);
      ht_lds[tid] = s;
      xw_lds[tid] = E_e[(size_t)e_data[b * Sv + 199] * DKv + tid];
    }
    __syncthreads();
    if (tid >= 64 && tid < 128) {
      const int p2 = p - 2;
      const float* zs = (p2 == 0) ? xw_lds : ht_lds;
      const float4* wp = (const float4*)&W5[k * 64 + 32 * p2];
      float acc5 = 0.0f;
#pragma unroll
      for (int i = 0; i < 8; i++) {
        float4 w = wp[i]; float4 z = ((const float4*)zs)[i];
        acc5 = fmaf(z.x, w.x, acc5); acc5 = fmaf(z.y, w.y, acc5);
        acc5 = fmaf(z.z, w.z, acc5); acc5 = fmaf(z.w, w.w, acc5);
      }
      red2[p2][k] = acc5;
    }
    __syncthreads();
    if (tid >= 32 && tid < 64) {
      const int kx = tid - 32;
      float s = fsig(b5[kx] + red2[0][kx] + red2[1][kx]);
#pragma unroll
      for (int m = 1; m < 32; m <<= 1) s += __shfl_xor(s, m);
      if (tid == 32) out[b * Sv + 199] = s * (1.0f / DKv);
    }
  }
}

extern "C" void kernel_launch(void* const* d_in, const int* in_sizes, int n_in,
                              void* d_out, int out_size, void* d_ws, size_t ws_size,
                              hipStream_t stream) {
  const int*   e_data   = (const int*)d_in[0];
  const int*   at_data  = (const int*)d_in[1];
  const int*   it_data  = (const int*)d_in[2];
  const float* a_data   = (const float*)d_in[3];
  const float* q_matrix = (const float*)d_in[4];
  const float* E_e      = (const float*)d_in[5];
  const float* E_at     = (const float*)d_in[6];
  const float* E_it     = (const float*)d_in[7];
  const float* W1 = (const float*)d_in[8];
  const float* b1 = (const float*)d_in[9];
  const float* W2 = (const float*)d_in[10];
  const float* b2 = (const float*)d_in[11];
  const float* W3 = (const float*)d_in[12];
  const float* b3 = (const float*)d_in[13];
  const float* W4 = (const float*)d_in[14];
  const float* b4 = (const float*)d_in[15];
  const float* W5 = (const float*)d_in[16];
  const float* b5 = (const float*)d_in[17];
  const float* h0 = (const float*)d_in[18];
  float* out = (float*)d_out;

  u64* partial = (u64*)d_ws;   // [3][Bv][NWG][DKv] tagged (tag<<32|value) words

  lpkt_init<<<1, 64, 0, stream>>>(out);
  lpkt_main<<<dim3(Bv * NWG), dim3(TPB), 0, stream>>>(
      e_data, at_data, it_data, a_data, q_matrix, E_e, E_at, E_it,
      W1, b1, W2, b2, W3, b3, W4, b4, W5, b5, h0, out, partial);
}

// Round 4
// 4904.169 us; speedup vs baseline: 2.5257x; 1.0582x over previous
//
#include <hip/hip_runtime.h>

#define Bv    64
#define Sv    200
#define DKv   32
#define NQ1v  4097
#define NWG   8      // workgroups per batch element
#define TPB   256    // threads per workgroup
#define ROWS  2      // rows per thread: 8*256*2 = 4096, +1 special
#define NSTEP 199

typedef unsigned long long u64;

__device__ __forceinline__ float fsig(float x) {
  return __builtin_amdgcn_rcpf(1.0f + __builtin_amdgcn_exp2f(x * -1.4426950408889634f));
}
__device__ __forceinline__ float ftanh_(float x) {
  return fmaf(2.0f, fsig(2.0f * x), -1.0f);
}
__device__ __forceinline__ u64 packvt(float v, unsigned tag) {
  return ((u64)tag << 32) | (u64)__float_as_uint(v);
}
// Fresh read: RMW executes at the coherence point, immune to stale L2 lines.
__device__ __forceinline__ u64 fresh_read(u64* p) {
  return __hip_atomic_fetch_add(p, 0ull, __ATOMIC_RELAXED, __HIP_MEMORY_SCOPE_AGENT);
}
__device__ __forceinline__ void fresh_write(u64* p, u64 v) {
  (void)__hip_atomic_exchange(p, v, __ATOMIC_RELAXED, __HIP_MEMORY_SCOPE_AGENT);
}

__global__ void lpkt_init(float* out) {
  int i = threadIdx.x;
  if (i < Bv) out[i * Sv] = 0.0f;
}

__global__ __launch_bounds__(TPB, 2) void lpkt_main(
    const int* __restrict__ e_data, const int* __restrict__ at_data,
    const int* __restrict__ it_data, const float* __restrict__ a_data,
    const float* __restrict__ q_matrix,
    const float* __restrict__ E_e, const float* __restrict__ E_at, const float* __restrict__ E_it,
    const float* __restrict__ W1, const float* __restrict__ b1,
    const float* __restrict__ W2, const float* __restrict__ b2,
    const float* __restrict__ W3, const float* __restrict__ b3,
    const float* __restrict__ W4, const float* __restrict__ b4,
    const float* __restrict__ W5, const float* __restrict__ b5,
    const float* __restrict__ h0, float* __restrict__ out,
    u64* __restrict__ partial)
{
  const int tid = threadIdx.x;
  const int wg  = blockIdx.x & (NWG - 1);
  const int b   = blockIdx.x / NWG;
  const int k   = tid & 31;
  const int p   = tid >> 5;          // 0..7
  const int nbase = wg * (TPB * ROWS);

  // ---- LDS: all weights resident (strides padded vs 32-bank aliasing)
  __shared__ float W23T[128 * 64];                 // [j][2k]=W2[k][j], [2k+1]=W3[k][j]
  __shared__ __align__(16) float W1L[32 * 100];    // row stride 100 (4-way on b128)
  __shared__ __align__(16) float W4L[32 * 100];
  __shared__ __align__(16) float W5L[32 * 68];
  __shared__ float bL[5 * 32];
  __shared__ __align__(16) float xw_lds[96];
  __shared__ __align__(16) float it_lds[DKv];
  __shared__ __align__(16) float lcA[DKv], lcB[DKv];
  __shared__ __align__(16) float ht_lds[DKv];
  __shared__ __align__(16) float LG_lds[DKv];
  __shared__ __align__(16) float c_lds[DKv];
  __shared__ __align__(16) float red[8][DKv];
  __shared__ __align__(16) float red2[8][DKv];
  __shared__ float ht_part[DKv];
  __shared__ __align__(16) float h49[DKv];

  // ---- one-time staging of weights into LDS
  for (int idx = tid; idx < 128 * 32; idx += TPB) {  // coalesced: j fast
    int j = idx & 127, kk = idx >> 7;
    W23T[j * 64 + 2 * kk]     = W2[kk * 128 + j];
    W23T[j * 64 + 2 * kk + 1] = W3[kk * 128 + j];
  }
  for (int idx = tid; idx < 32 * 96; idx += TPB) {
    int r = idx / 96, c = idx % 96;
    W1L[r * 100 + c] = W1[idx];
    W4L[r * 100 + c] = W4[idx];
  }
  for (int idx = tid; idx < 32 * 64; idx += TPB) {
    int r = idx >> 6, c = idx & 63;
    W5L[r * 68 + c] = W5[idx];
  }
  if (tid < 32) {
    bL[0 * 32 + tid] = b1[tid]; bL[1 * 32 + tid] = b2[tid];
    bL[2 * 32 + tid] = b3[tid]; bL[3 * 32 + tid] = b4[tid];
    bL[4 * 32 + tid] = b5[tid];
  }
  if (tid < DKv) { ht_part[tid] = 0.0f; lcB[tid] = 0.0f; }   // lcB = lp at t=0
  if (wg == 0 && tid < DKv) h49[tid] = h0[4096 * DKv + tid];

  // ---- persistent register state
  float h[ROWS][DKv];
#pragma unroll
  for (int r = 0; r < ROWS; r++) {
    const float4* hp = (const float4*)(h0 + (size_t)(nbase + r * TPB + tid) * DKv);
#pragma unroll
    for (int i = 0; i < 8; i++) {
      float4 v = hp[i];
      h[r][4*i] = v.x; h[r][4*i+1] = v.y; h[r][4*i+2] = v.z; h[r][4*i+3] = v.w;
    }
  }
  const int e0 = e_data[b * Sv];
  const float* q0 = q_matrix + (size_t)e0 * NQ1v;
  float qc[ROWS];
#pragma unroll
  for (int r = 0; r < ROWS; r++) qc[r] = q0[nbase + r * TPB + tid];
  float qc49 = (wg == 0 && tid < DKv) ? q0[4096] : 0.0f;
  __syncthreads();

  // ---- phase 0: h_tilde0 via sparse LDS atomics; post tag=1
#pragma unroll
  for (int r = 0; r < ROWS; r++) {
    if (qc[r] != 0.0f) {
#pragma unroll
      for (int kk = 0; kk < DKv; kk++) atomicAdd(&ht_part[kk], h[r][kk]);
    }
  }
  if (wg == 0 && tid < DKv && qc49 != 0.0f) atomicAdd(&ht_part[tid], h49[tid]);
  __syncthreads();
  if (tid < DKv)
    fresh_write(&partial[((size_t)(1 % 3) * Bv + b) * (NWG * DKv) + wg * DKv + tid],
                packvt(ht_part[tid], 1u));

  // =================== time loop ===================
  for (int t = 0; t < NSTEP; t++) {
    float* lc_cur  = (t & 1) ? lcB : lcA;
    float* lc_prev = (t & 1) ? lcA : lcB;
    const unsigned tau_g = (unsigned)(t + 1);
    const unsigned tau_p = (unsigned)(t + 2);

    // ---- A: prefetch q_next + stage embeddings
    const int ecur  = e_data[b * Sv + t];
    const int enext = e_data[b * Sv + t + 1];
    const int atc   = at_data[b * Sv + t];
    const int itc   = it_data[b * Sv + t];
    const float av  = a_data[b * Sv + t];
    const float* qnr = q_matrix + (size_t)enext * NQ1v;
    float qn[ROWS];
#pragma unroll
    for (int r = 0; r < ROWS; r++) qn[r] = qnr[nbase + r * TPB + tid];
    float qn49 = (wg == 0 && tid < DKv) ? qnr[4096] : 0.0f;

    if (tid < 96)
      xw_lds[tid] = (tid < 32) ? E_e[(size_t)ecur * DKv + tid]
                  : (tid < 64) ? E_at[(size_t)atc * DKv + (tid - 32)] : av;
    else if (tid < 128)
      it_lds[tid - 96] = E_it[(size_t)itc * DKv + (tid - 96)];

    // ---- B: bulk matvec W4h·h (uniform W4 -> s_load; overlaps the sync wait)
    float acc[ROWS][DKv];
#pragma unroll
    for (int kk = 0; kk < DKv; kk++) {
      float a0 = 0.0f, a1 = 0.0f;
#pragma unroll
      for (int d = 0; d < DKv; d += 4) {
        float4 w = *(const float4*)&W4[kk * 96 + d];
        a0 = fmaf(w.x, h[0][d+0], a0); a1 = fmaf(w.x, h[1][d+0], a1);
        a0 = fmaf(w.y, h[0][d+1], a0); a1 = fmaf(w.y, h[1][d+1], a1);
        a0 = fmaf(w.z, h[0][d+2], a0); a1 = fmaf(w.z, h[1][d+2], a1);
        a0 = fmaf(w.w, h[0][d+3], a0); a1 = fmaf(w.w, h[1][d+3], a1);
      }
      acc[0][kk] = a0; acc[1][kk] = a1;
    }
    __syncthreads();   // B1

    // ---- S1 (wave-parallel): w0: fresh poll+gather | w1: lc matvec | w2: idle
    if (tid < DKv) {
      u64* pb = partial + ((size_t)(tau_g % 3) * Bv + b) * (NWG * DKv) + tid;
      u64 v[NWG];
      for (;;) {
        bool ok = true;
#pragma unroll
        for (int w2 = 0; w2 < NWG; w2++) {
          v[w2] = fresh_read(&pb[w2 * DKv]);
          ok = ok && ((unsigned)(v[w2] >> 32) == tau_g);
        }
        if (ok) break;
        __builtin_amdgcn_s_sleep(2);
      }
      float s = 0.0f;
#pragma unroll
      for (int w2 = 0; w2 < NWG; w2++) s += __uint_as_float((unsigned)v[w2]);
      ht_lds[tid] = s;
    } else if (tid >= 64 && tid < 96) {
      const int kx = tid - 64;
      float s = bL[0 * 32 + kx];
      const float4* wp = (const float4*)&W1L[kx * 100];
      const float4* xp = (const float4*)xw_lds;
#pragma unroll
      for (int i = 0; i < 24; i++) {
        float4 w = wp[i]; float4 x = xp[i];
        s = fmaf(x.x, w.x, s); s = fmaf(x.y, w.y, s);
        s = fmaf(x.z, w.z, s); s = fmaf(x.w, w.w, s);
      }
      lc_cur[kx] = s;
    }
    __syncthreads();   // B3

    // ---- D: lg/gl split-8 (b64 interleaved W23T: 2-way = free)
    {
      const int seg = p >> 1;                     // 0:lp 1:it 2:lc 3:ht
      const float* sp = (seg == 0) ? lc_prev : (seg == 1) ? it_lds
                      : (seg == 2) ? lc_cur  : ht_lds;
      const int off = (p & 1) * 16;
      float xv[16];
#pragma unroll
      for (int i = 0; i < 4; i++) {
        float4 v = ((const float4*)(sp + off))[i];
        xv[4*i] = v.x; xv[4*i+1] = v.y; xv[4*i+2] = v.z; xv[4*i+3] = v.w;
      }
      float s2 = 0.0f, s3 = 0.0f;
      const int jb = 16 * p;
#pragma unroll
      for (int i = 0; i < 16; i++) {
        float2 w = *(const float2*)&W23T[(jb + i) * 64 + 2 * k];
        s2 = fmaf(xv[i], w.x, s2);
        s3 = fmaf(xv[i], w.y, s3);
      }
      red[p][k] = s2; red2[p][k] = s3;
    }
    __syncthreads();   // B4

    // ---- E: w0: LG | w2: zero ht_part
    if (tid < DKv) {
      float s2 = bL[1 * 32 + tid], s3 = bL[2 * 32 + tid];
#pragma unroll
      for (int pp = 0; pp < 8; pp++) { s2 += red[pp][tid]; s3 += red2[pp][tid]; }
      LG_lds[tid] = fsig(s3) * (ftanh_(s2) + 1.0f) * 0.5f;
    } else if (tid >= 128 && tid < 160) ht_part[tid - 128] = 0.0f;
    __syncthreads();   // B5

    // ---- F: c split-8 (all) | y partials (wg0 wave1, t>=1)
    {
      const float* up = (p < 4) ? (LG_lds + 8 * p) : (it_lds + 8 * (p - 4));
      const float4* wp = (const float4*)&W4L[k * 100 + 32 + 8 * p];
      float4 w0 = wp[0], w1 = wp[1];
      float pc = 0.0f;
      pc = fmaf(up[0], w0.x, pc); pc = fmaf(up[1], w0.y, pc);
      pc = fmaf(up[2], w0.z, pc); pc = fmaf(up[3], w0.w, pc);
      pc = fmaf(up[4], w1.x, pc); pc = fmaf(up[5], w1.y, pc);
      pc = fmaf(up[6], w1.z, pc); pc = fmaf(up[7], w1.w, pc);
      red[p][k] = pc;
    }
    if (wg == 0 && t >= 1 && tid >= 64 && tid < 128) {
      const int p2 = p - 2;
      const float* zs = (p2 == 0) ? xw_lds : ht_lds;   // xw[0:32] = E_e[e_data[t]]
      const float4* wp = (const float4*)&W5L[k * 68 + 32 * p2];
      float acc5 = 0.0f;
#pragma unroll
      for (int i = 0; i < 8; i++) {
        float4 w = wp[i]; float4 z = ((const float4*)zs)[i];
        acc5 = fmaf(z.x, w.x, acc5); acc5 = fmaf(z.y, w.y, acc5);
        acc5 = fmaf(z.z, w.z, acc5); acc5 = fmaf(z.w, w.w, acc5);
      }
      red2[p2][k] = acc5;
    }
    __syncthreads();   // B6

    // ---- G: w0: c sum | wg0 w1(hi): y finish
    if (tid < DKv) {
      float s = bL[3 * 32 + tid];
#pragma unroll
      for (int pp = 0; pp < 8; pp++) s += red[pp][tid];
      c_lds[tid] = s;
    } else if (wg == 0 && t >= 1 && tid >= 96 && tid < 128) {
      const int kx = tid - 96;
      float s = fsig(bL[4 * 32 + kx] + red2[0][kx] + red2[1][kx]);
#pragma unroll
      for (int m = 1; m < 32; m <<= 1) s += __shfl_xor(s, m);
      if (tid == 96) out[b * Sv + t] = s * (1.0f / DKv);
    }
    __syncthreads();   // B7

    // ---- H: update h in place; sparse-atomic h_tilde contributions
    {
      float c_r[DKv], lg_r[DKv];
#pragma unroll
      for (int i = 0; i < 8; i++) {
        float4 cv = ((const float4*)c_lds)[i];
        float4 gv = ((const float4*)LG_lds)[i];
        c_r[4*i] = cv.x; c_r[4*i+1] = cv.y; c_r[4*i+2] = cv.z; c_r[4*i+3] = cv.w;
        lg_r[4*i] = gv.x; lg_r[4*i+1] = gv.y; lg_r[4*i+2] = gv.z; lg_r[4*i+3] = gv.w;
      }
#pragma unroll
      for (int r = 0; r < ROWS; r++) {
        const float qcr = qc[r];
#pragma unroll
        for (int kk = 0; kk < DKv; kk++) {
          float g = fsig(acc[r][kk] + c_r[kk]);
          h[r][kk] = fmaf(g, h[r][kk], qcr * lg_r[kk]);
        }
        if (qn[r] != 0.0f) {
#pragma unroll
          for (int kk = 0; kk < DKv; kk++) atomicAdd(&ht_part[kk], h[r][kk]);
        }
        qc[r] = qn[r];
      }
    }
    if (wg == 0 && tid < DKv) {      // special row 4096 (LDS-resident)
      float hh[DKv];
#pragma unroll
      for (int i = 0; i < 8; i++) {
        float4 v = ((const float4*)h49)[i];
        hh[4*i] = v.x; hh[4*i+1] = v.y; hh[4*i+2] = v.z; hh[4*i+3] = v.w;
      }
      float a = c_lds[tid];
#pragma unroll
      for (int d = 0; d < DKv; d += 4) {
        float4 w = *(const float4*)&W4L[tid * 100 + d];
        a = fmaf(w.x, hh[d+0], a); a = fmaf(w.y, hh[d+1], a);
        a = fmaf(w.z, hh[d+2], a); a = fmaf(w.w, hh[d+3], a);
      }
      float hn = fmaf(fsig(a), h49[tid], qc49 * LG_lds[tid]);
      h49[tid] = hn;
      if (qn49 != 0.0f) atomicAdd(&ht_part[tid], hn);
      qc49 = qn49;
    }
    __syncthreads();   // B8

    // ---- I: post tagged partial via atomicExch (memory-side, promptly visible)
    if (tid < DKv)
      fresh_write(&partial[((size_t)(tau_p % 3) * Bv + b) * (NWG * DKv) + wg * DKv + tid],
                  packvt(ht_part[tid], tau_p));
  }

  // =================== epilogue: y for pred index 199 (wg0 only) ===================
  if (wg == 0) {
    const unsigned tau_f = (unsigned)(NSTEP + 1);   // 200
    if (tid < DKv) {
      u64* pb = partial + ((size_t)(tau_f % 3) * Bv + b) * (NWG * DKv) + tid;
      u64 v[NWG];
      for (;;) {
        bool ok = true;
#pragma unroll
        for (int w2 = 0; w2 < NWG; w2++) {
          v[w2] = fresh_read(&pb[w2 * DKv]);
          ok = ok && ((unsigned)(v[w2] >> 32) == tau_f);
        }
        if (ok) break;
        __builtin_amdgcn_s_sleep(2);
      }
      float s = 0.0f;
#pragma unroll
      for (int w2 = 0; w2 < NWG; w2++) s += __uint_as_float((unsigned)v[w2]);
      ht_lds[tid] = s;
      xw_lds[tid] = E_e[(size_t)e_data[b * Sv + 199] * DKv + tid];
    }
    __syncthreads();
    if (tid >= 64 && tid < 128) {
      const int p2 = p - 2;
      const float* zs = (p2 == 0) ? xw_lds : ht_lds;
      const float4* wp = (const float4*)&W5L[k * 68 + 32 * p2];
      float acc5 = 0.0f;
#pragma unroll
      for (int i = 0; i < 8; i++) {
        float4 w = wp[i]; float4 z = ((const float4*)zs)[i];
        acc5 = fmaf(z.x, w.x, acc5); acc5 = fmaf(z.y, w.y, acc5);
        acc5 = fmaf(z.z, w.z, acc5); acc5 = fmaf(z.w, w.w, acc5);
      }
      red2[p2][k] = acc5;
    }
    __syncthreads();
    if (tid >= 96 && tid < 128) {
      const int kx = tid - 96;
      float s = fsig(bL[4 * 32 + kx] + red2[0][kx] + red2[1][kx]);
#pragma unroll
      for (int m = 1; m < 32; m <<= 1) s += __shfl_xor(s, m);
      if (tid == 96) out[b * Sv + 199] = s * (1.0f / DKv);
    }
  }
}

extern "C" void kernel_launch(void* const* d_in, const int* in_sizes, int n_in,
                              void* d_out, int out_size, void* d_ws, size_t ws_size,
                              hipStream_t stream) {
  const int*   e_data   = (const int*)d_in[0];
  const int*   at_data  = (const int*)d_in[1];
  const int*   it_data  = (const int*)d_in[2];
  const float* a_data   = (const float*)d_in[3];
  const float* q_matrix = (const float*)d_in[4];
  const float* E_e      = (const float*)d_in[5];
  const float* E_at     = (const float*)d_in[6];
  const float* E_it     = (const float*)d_in[7];
  const float* W1 = (const float*)d_in[8];
  const float* b1 = (const float*)d_in[9];
  const float* W2 = (const float*)d_in[10];
  const float* b2 = (const float*)d_in[11];
  const float* W3 = (const float*)d_in[12];
  const float* b3 = (const float*)d_in[13];
  const float* W4 = (const float*)d_in[14];
  const float* b4 = (const float*)d_in[15];
  const float* W5 = (const float*)d_in[16];
  const float* b5 = (const float*)d_in[17];
  const float* h0 = (const float*)d_in[18];
  float* out = (float*)d_out;

  u64* partial = (u64*)d_ws;   // [3][Bv][NWG][DKv] tagged (tag<<32|value) words

  lpkt_init<<<1, 64, 0, stream>>>(out);
  lpkt_main<<<dim3(Bv * NWG), dim3(TPB), 0, stream>>>(
      e_data, at_data, it_data, a_data, q_matrix, E_e, E_at, E_it,
      W1, b1, W2, b2, W3, b3, W4, b4, W5, b5, h0, out, partial);
}